// Round 15
// baseline (108.394 us; speedup 1.0000x reference)
//
#include <hip/hip_runtime.h>
#include <hip/hip_bf16.h>
#include <math.h>

// Laplacian-pyramid L1 loss, (2,1,64,256,256), 5 levels, sigma=1 (9-tap), scipy-reflect.
// loss = sum_l mean |lap_pyramid(input-target)[l]| (linearity of the pyramid).
// 9 plain launches; losses packed into ladder launches; no cross-block sync
// (r5/r7), no serial single-block kernels (r3/r12). r15: 64x64 loss tiles for
// L0/L1 (half the blocks, less halo, fewer syncs).
//  D1 k1l0(+bf16 DIFF x<132 + x>=132 partials)
//  D2 k2s0: T1->C1 (512)
//  D3 FAT[k1s1 (256) || k3_0: C1->V0 (1024)]
//  D4 FAT[k2s1 (64) || k4-L0 (1536, 64x64 tiles, V0+DIFF)]
//  D5 FAT[k1s2 (64) || k4-L1 (256, 64x64 tiles, fused-z dn=C2, cur=C1)]
//  D6 k2s2 (8)
//  D7 FAT[k1s3 (16) || k4-L2 (64, fused-z dn=C3, cur=C2)]
//  D8 tailpar (24): LDS chain Tl3->C4(->Tl4->C5); L3+L4 losses via dev_k4f
//  D9 kreduce (2904 partials)

struct GW { float w[9]; float A, B; };

__device__ __forceinline__ int ridx(int p, int n) {
    // scipy 'reflect' (symmetric) for power-of-two n; valid for p >= -2n
    int m = 2 * n;
    int q = (p + m) & (m - 1);
    return (q < n) ? q : (m - 1 - q);
}

__device__ __forceinline__ float block_sum256(float v) {
    #pragma unroll
    for (int off = 32; off > 0; off >>= 1) v += __shfl_down(v, off, 64);
    __shared__ float wp[4];
    int tid = threadIdx.x;
    if ((tid & 63) == 0) wp[tid >> 6] = v;
    __syncthreads();
    return wp[0] + wp[1] + wp[2] + wp[3];
}

__device__ __forceinline__ float block_sum1024(float v) {
    #pragma unroll
    for (int off = 32; off > 0; off >>= 1) v += __shfl_down(v, off, 64);
    __shared__ float wp[16];
    int tid = threadIdx.x;
    if ((tid & 63) == 0) wp[tid >> 6] = v;
    __syncthreads();
    float t = 0.f;
    if (tid == 0) {
        #pragma unroll
        for (int w = 0; w < 16; ++w) t += wp[w];
    }
    return t;
}

// ---------------------------------------------------------------------------
// k1l0: level-0 fused W+H gaussian of (in - tg) -> T1 (even y,x).
// Also: bf16 DIFF for x<132, and the x>=132 |diff| sums as partials P[0..1024).
template<bool WDIFF>
__global__ __launch_bounds__(256)
void k1l0(const float* __restrict__ in, const float* __restrict__ tg,
          float* __restrict__ T1, __hip_bfloat16* __restrict__ DIFF,
          float* __restrict__ P, GW g)
{
    const int H = 256, W = 256, Wd = 128;
    const int x0d = blockIdx.x * 64, y0d = blockIdx.y * 16, slice = blockIdx.z;
    __shared__ float raw[40][136];
    __shared__ float mid[40][64];
    const size_t in_off  = (size_t)slice * H * W;
    const size_t out_off = (size_t)slice * 128 * 128;
    const int tid = threadIdx.x;
    const int gy0 = 2*y0d - 4, gx0 = 2*x0d - 4;
    for (int i = tid; i < 40*32; i += 256) {
        int rr = i >> 5, c4 = (i & 31) + 1;
        int gy = ridx(gy0 + rr, H);
        size_t base = in_off + (size_t)gy * W + gx0 + 4*c4;
        float4 v = *(const float4*)(in + base);
        float4 b = *(const float4*)(tg + base);
        v.x -= b.x; v.y -= b.y; v.z -= b.z; v.w -= b.w;
        *(float4*)&raw[rr][4*c4] = v;
    }
    for (int i = tid; i < 40*8; i += 256) {
        int rr = i >> 3, j = i & 7;
        int cc = (j < 4) ? j : (128 + j);
        int gy = ridx(gy0 + rr, H);
        int gx = ridx(gx0 + cc, W);
        size_t idx = in_off + (size_t)gy * W + gx;
        raw[rr][cc] = in[idx] - tg[idx];
    }
    __syncthreads();
    if (WDIFF) {
        if (blockIdx.x == 0) {
            for (int i = tid; i < 32*128; i += 256) {
                int r = i >> 7, c = i & 127;
                DIFF[in_off + (size_t)(2*y0d + r) * W + c] =
                    __float2bfloat16(raw[4 + r][4 + c]);
            }
        } else {
            for (int i = tid; i < 32*4; i += 256) {
                int r = i >> 2, c = i & 3;
                DIFF[in_off + (size_t)(2*y0d + r) * W + 128 + c] =
                    __float2bfloat16(raw[4 + r][4 + c]);
            }
        }
    }
    if (blockIdx.x == 1) {
        // x >= 132 loss contribution (up == 0 there)
        float lsum = 0.f;
        for (int i = tid; i < 32*124; i += 256) {
            int r = i / 124, c = i - r*124;
            lsum += fabsf(raw[4 + r][8 + c]);
        }
        float tot = block_sum256(lsum);
        if (tid == 0)
            P[blockIdx.y + 8*blockIdx.z] = tot * (1.f / 8388608.f);
    }
    for (int i = tid; i < 40*64; i += 256) {
        int rr = i >> 6, c = i & 63;
        float s = 0.f;
        #pragma unroll
        for (int k = 0; k < 9; ++k) s = fmaf(g.w[k], raw[rr][2*c + k], s);
        mid[rr][c] = s;
    }
    __syncthreads();
    {
        int r = tid >> 6, c = tid & 63;
        int ox = x0d + c;
        #pragma unroll
        for (int j = 0; j < 4; ++j) {
            int oy = y0d + r*4 + j;
            int rb = 2*(r*4 + j);
            float s = 0.f;
            #pragma unroll
            for (int k = 0; k < 9; ++k) s = fmaf(g.w[k], mid[rb + k][c], s);
            T1[out_off + (size_t)oy * Wd + ox] = s;
        }
    }
}

// ---------------------------------------------------------------------------
// dev_k2_elem: D-axis gaussian + batch(2) reflect mix at even z. One float4/elem.
__device__ void dev_k2_elem(long i, const float4* __restrict__ T, float4* __restrict__ O,
                            int D, int Dd, int M4, const GW& g)
{
    if (i >= (long)Dd * M4) return;
    int zd = (int)(i / M4);
    int q  = (int)(i - (long)zd * M4);
    float4 s0 = {0,0,0,0}, s1 = {0,0,0,0};
    #pragma unroll
    for (int k = 0; k < 9; ++k) {
        int zp = 2*zd - 4 + k;
        int zk = (zp >= 0 && zp < D) ? zp : ridx(zp, D);
        float4 a = T[(size_t)zk * M4 + q];
        float4 b = T[(size_t)(D + zk) * M4 + q];
        s0.x = fmaf(g.w[k], a.x, s0.x); s0.y = fmaf(g.w[k], a.y, s0.y);
        s0.z = fmaf(g.w[k], a.z, s0.z); s0.w = fmaf(g.w[k], a.w, s0.w);
        s1.x = fmaf(g.w[k], b.x, s1.x); s1.y = fmaf(g.w[k], b.y, s1.y);
        s1.z = fmaf(g.w[k], b.z, s1.z); s1.w = fmaf(g.w[k], b.w, s1.w);
    }
    float4 o0, o1;
    o0.x = g.A*s0.x + g.B*s1.x; o0.y = g.A*s0.y + g.B*s1.y;
    o0.z = g.A*s0.z + g.B*s1.z; o0.w = g.A*s0.w + g.B*s1.w;
    o1.x = g.B*s0.x + g.A*s1.x; o1.y = g.B*s0.y + g.A*s1.y;
    o1.z = g.B*s0.z + g.A*s1.z; o1.w = g.B*s0.w + g.A*s1.w;
    O[(size_t)zd * M4 + q] = o0;
    O[(size_t)(Dd + zd) * M4 + q] = o1;
}

__global__ __launch_bounds__(256)
void k2s(const float* __restrict__ Tin, float* __restrict__ Cout,
         int D, int Dd, int M4, GW g)
{
    long i = (long)blockIdx.x * 256 + threadIdx.x;
    dev_k2_elem(i, (const float4*)Tin, (float4*)Cout, D, Dd, M4, g);
}

// ---------------------------------------------------------------------------
// dev_k1_slice: fused W+H gaussian on one (H,W) slice, even (y,x) -> (Hd,Wd).
__device__ void dev_k1_slice(const float* __restrict__ inA, float* __restrict__ out,
                             int x0d, int y0d, int slice, int H, int W, int Hd, int Wd,
                             const GW& g)
{
    __shared__ float raw[40][136];
    __shared__ float mid[40][64];
    const size_t in_off  = (size_t)slice * H * W;
    const size_t out_off = (size_t)slice * Hd * Wd;
    const int tid = threadIdx.x;
    const int gy0 = 2*y0d - 4, gx0 = 2*x0d - 4;
    if (2*x0d + 127 < W) {
        for (int i = tid; i < 40*32; i += 256) {
            int rr = i >> 5, c4 = (i & 31) + 1;
            int gy = ridx(gy0 + rr, H);
            *(float4*)&raw[rr][4*c4] =
                *(const float4*)(inA + in_off + (size_t)gy * W + gx0 + 4*c4);
        }
        for (int i = tid; i < 40*8; i += 256) {
            int rr = i >> 3, j = i & 7;
            int cc = (j < 4) ? j : (128 + j);
            int gy = ridx(gy0 + rr, H), gx = ridx(gx0 + cc, W);
            raw[rr][cc] = inA[in_off + (size_t)gy * W + gx];
        }
    } else {
        for (int i = tid; i < 40*136; i += 256) {
            int rr = i / 136, cc = i - rr*136;
            int gy = ridx(gy0 + rr, H), gx = ridx(gx0 + cc, W);
            raw[rr][cc] = inA[in_off + (size_t)gy * W + gx];
        }
    }
    __syncthreads();
    for (int i = tid; i < 40*64; i += 256) {
        int rr = i >> 6, c = i & 63;
        float s = 0.f;
        #pragma unroll
        for (int k = 0; k < 9; ++k) s = fmaf(g.w[k], raw[rr][2*c + k], s);
        mid[rr][c] = s;
    }
    __syncthreads();
    {
        int r = tid >> 6, c = tid & 63;
        int ox = x0d + c;
        #pragma unroll
        for (int j = 0; j < 4; ++j) {
            int oy = y0d + r*4 + j;
            if (oy < Hd && ox < Wd) {
                int rb = 2*(r*4 + j);
                float s = 0.f;
                #pragma unroll
                for (int k = 0; k < 9; ++k) s = fmaf(g.w[k], mid[rb + k][c], s);
                out[out_off + (size_t)oy * Wd + ox] = s;
            }
        }
    }
}

// ---------------------------------------------------------------------------
// dev_k3_elem: D-filter of zero-stuffed dn + batch mix (upsample D/batch), x8.
__device__ void dev_k3_elem(long i, const float4* __restrict__ Dn, float4* __restrict__ O,
                            int D, int Dd, int M4, const GW& g)
{
    if (i >= (long)D * M4) return;
    int z = (int)(i / M4);
    int q = (int)(i - (long)z * M4);
    float4 s0 = {0,0,0,0}, s1 = {0,0,0,0};
    auto f4 = [](float4& a, float w, const float4 b) {
        a.x = fmaf(w, b.x, a.x); a.y = fmaf(w, b.y, a.y);
        a.z = fmaf(w, b.z, a.z); a.w = fmaf(w, b.w, a.w);
    };
    if (z >= 4 && z + 4 < D) {
        if ((z & 1) == 0) {
            int base = (z >> 1) - 2;
            #pragma unroll
            for (int kk = 0; kk < 5; ++kk) {
                f4(s0, g.w[2*kk], Dn[(size_t)(base + kk) * M4 + q]);
                f4(s1, g.w[2*kk], Dn[(size_t)(Dd + base + kk) * M4 + q]);
            }
        } else {
            int base = (z - 3) >> 1;
            #pragma unroll
            for (int kk = 0; kk < 4; ++kk) {
                f4(s0, g.w[2*kk+1], Dn[(size_t)(base + kk) * M4 + q]);
                f4(s1, g.w[2*kk+1], Dn[(size_t)(Dd + base + kk) * M4 + q]);
            }
        }
    } else {
        #pragma unroll
        for (int k = 0; k < 9; ++k) {
            int zk = ridx(z - 4 + k, D);
            if (!(zk & 1)) {
                int j = zk >> 1;
                f4(s0, g.w[k], Dn[(size_t)j * M4 + q]);
                f4(s1, g.w[k], Dn[(size_t)(Dd + j) * M4 + q]);
            }
        }
    }
    float4 o0, o1;
    o0.x = 8.f*(g.A*s0.x + g.B*s1.x); o0.y = 8.f*(g.A*s0.y + g.B*s1.y);
    o0.z = 8.f*(g.A*s0.z + g.B*s1.z); o0.w = 8.f*(g.A*s0.w + g.B*s1.w);
    o1.x = 8.f*(g.B*s0.x + g.A*s1.x); o1.y = 8.f*(g.B*s0.y + g.A*s1.y);
    o1.z = 8.f*(g.B*s0.z + g.A*s1.z); o1.w = 8.f*(g.B*s0.w + g.A*s1.w);
    O[(size_t)z * M4 + q] = o0;
    O[(size_t)(D + z) * M4 + q] = o1;
}

// ---------------------------------------------------------------------------
// dev_k4v064: level-0 loss, 64x64 tile from materialized V0 + bf16 DIFF.
__device__ void dev_k4v064(int local, const float* __restrict__ V0,
                           const __hip_bfloat16* __restrict__ DIFF,
                           const float* __restrict__ in, const float* __restrict__ tg,
                           int use_diff, float* __restrict__ P, const GW& g)
{
    __shared__ float vt[36][72];
    __shared__ float mid[36][64];
    const int H = 256, W = 256, Hd = 128, Wd = 128, Md = 128*128;
    const int s = local / 12;
    const int rem = local - s*12;
    const int ty = rem / 3, tx = rem - ty*3;
    const int x0 = tx*64, y0 = ty*64;
    const int tid = threadIdx.x;
    const int vy0 = (y0 >> 1) - 2;
    const size_t v_off = (size_t)s * Md;
    for (int i = tid; i < 36*72; i += 256) {
        int rr = i / 72, cc = i - rr*72;
        int vy = vy0 + rr;
        int txx = x0 - 4 + cc;
        if (txx < 0) txx = -1 - txx;
        float v = 0.f;
        if (vy >= 0 && vy < Hd && txx < Wd) v = V0[v_off + (size_t)vy * Wd + txx];
        vt[rr][cc] = v;
    }
    __syncthreads();
    for (int i = tid; i < 36*64; i += 256) {
        int rr = i >> 6, c = i & 63;
        float sv = 0.f;
        #pragma unroll
        for (int k = 0; k < 9; ++k) sv = fmaf(g.w[k], vt[rr][c + k], sv);
        mid[rr][c] = sv;
    }
    __syncthreads();
    const bool yin = (y0 >= 4) && (y0 + 67 < H);
    const int c = tid & 63;
    const int ry_base = (tid >> 6) * 16;
    const int ox = x0 + c;
    const size_t c_off = (size_t)s * H * W;
    float lsum = 0.f;
    #pragma unroll
    for (int j = 0; j < 16; ++j) {
        int ry = ry_base + j;          // parity(ry) == parity(j)
        int oy = y0 + ry;
        if (ox < 132 && oy < H) {
            float sv = 0.f;
            if (yin) {
                if (!(j & 1)) {
                    int r0 = ry >> 1;
                    sv = g.w[0]*mid[r0][c] + g.w[2]*mid[r0+1][c] + g.w[4]*mid[r0+2][c]
                       + g.w[6]*mid[r0+3][c] + g.w[8]*mid[r0+4][c];
                } else {
                    int r0 = ((ry - 3) >> 1) + 2;
                    sv = g.w[1]*mid[r0][c] + g.w[3]*mid[r0+1][c]
                       + g.w[5]*mid[r0+2][c] + g.w[7]*mid[r0+3][c];
                }
            } else {
                #pragma unroll
                for (int k = 0; k < 9; ++k) {
                    int gy = ridx(oy - 4 + k, H);
                    if (!(gy & 1)) sv = fmaf(g.w[k], mid[(gy >> 1) - vy0][c], sv);
                }
            }
            size_t idx = c_off + (size_t)oy * W + ox;
            float cv = use_diff ? __bfloat162float(DIFF[idx]) : (in[idx] - tg[idx]);
            lsum += fabsf(cv - sv);
        }
    }
    float tot = block_sum256(lsum);
    if (tid == 0) P[1024 + local] = tot * (1.f / 8388608.f);
}

// ---------------------------------------------------------------------------
// dev_k4f64: 64x64-tile loss with fused-z staging from global dn (level 1).
__device__ void dev_k4f64(int local, const float* __restrict__ dnb,
                          const float* __restrict__ cur, float* __restrict__ Pslot,
                          int D, int H, int ntx, int nty, float invn, const GW& g)
{
    __shared__ float vt[36][72];
    __shared__ float mid[36][64];
    const int W = H, Dd = D >> 1, Hd = H >> 1, Wd = W >> 1, Md = Hd * Wd;
    const int s = local / (ntx*nty);
    const int rem = local - s*(ntx*nty);
    const int ty = rem / ntx, tx = rem - ty*ntx;
    const int x0 = tx*64, y0 = ty*64;
    const int b = s / D, z = s - b*D;
    const float* dn0 = dnb + (size_t)b * Dd * Md;
    const float* dn1 = dnb + (size_t)(1 - b) * Dd * Md;
    const int tid = threadIdx.x;
    const int vy0 = (y0 >> 1) - 2;

    const bool zin = (z >= 4) && (z + 4 < D);
    if (zin && !(z & 1)) {
        const int j0 = (z >> 1) - 2;
        for (int i = tid; i < 36*72; i += 256) {
            int rr = i / 72, cc = i - rr*72;
            int vy = vy0 + rr;
            int txx = x0 - 4 + cc;
            if (txx < 0) txx = -1 - txx;
            float v = 0.f;
            if (vy >= 0 && vy < Hd && txx < Wd) {
                size_t o = (size_t)vy * Wd + txx;
                float s0 = 0.f, s1 = 0.f;
                #pragma unroll
                for (int t = 0; t < 5; ++t) {
                    s0 = fmaf(g.w[2*t], dn0[(size_t)(j0 + t) * Md + o], s0);
                    s1 = fmaf(g.w[2*t], dn1[(size_t)(j0 + t) * Md + o], s1);
                }
                v = 8.f * (g.A*s0 + g.B*s1);
            }
            vt[rr][cc] = v;
        }
    } else if (zin) {
        const int j0 = (z - 3) >> 1;
        for (int i = tid; i < 36*72; i += 256) {
            int rr = i / 72, cc = i - rr*72;
            int vy = vy0 + rr;
            int txx = x0 - 4 + cc;
            if (txx < 0) txx = -1 - txx;
            float v = 0.f;
            if (vy >= 0 && vy < Hd && txx < Wd) {
                size_t o = (size_t)vy * Wd + txx;
                float s0 = 0.f, s1 = 0.f;
                #pragma unroll
                for (int t = 0; t < 4; ++t) {
                    s0 = fmaf(g.w[2*t+1], dn0[(size_t)(j0 + t) * Md + o], s0);
                    s1 = fmaf(g.w[2*t+1], dn1[(size_t)(j0 + t) * Md + o], s1);
                }
                v = 8.f * (g.A*s0 + g.B*s1);
            }
            vt[rr][cc] = v;
        }
    } else {
        for (int i = tid; i < 36*72; i += 256) {
            int rr = i / 72, cc = i - rr*72;
            int vy = vy0 + rr;
            int txx = x0 - 4 + cc;
            if (txx < 0) txx = -1 - txx;
            float v = 0.f;
            if (vy >= 0 && vy < Hd && txx < Wd) {
                size_t o = (size_t)vy * Wd + txx;
                float s0 = 0.f, s1 = 0.f;
                #pragma unroll
                for (int k = 0; k < 9; ++k) {
                    int zk = ridx(z - 4 + k, D);
                    if (!(zk & 1)) {
                        int j = zk >> 1;
                        s0 = fmaf(g.w[k], dn0[(size_t)j * Md + o], s0);
                        s1 = fmaf(g.w[k], dn1[(size_t)j * Md + o], s1);
                    }
                }
                v = 8.f * (g.A*s0 + g.B*s1);
            }
            vt[rr][cc] = v;
        }
    }
    __syncthreads();
    for (int i = tid; i < 36*64; i += 256) {
        int rr = i >> 6, c = i & 63;
        float sv = 0.f;
        #pragma unroll
        for (int k = 0; k < 9; ++k) sv = fmaf(g.w[k], vt[rr][c + k], sv);
        mid[rr][c] = sv;
    }
    __syncthreads();
    const bool yin = (y0 >= 4) && (y0 + 67 < H);
    const int c = tid & 63;
    const int ry_base = (tid >> 6) * 16;
    const int ox = x0 + c;
    const size_t c_off = (size_t)s * H * W;
    float lsum = 0.f;
    #pragma unroll
    for (int j = 0; j < 16; ++j) {
        int ry = ry_base + j;
        int oy = y0 + ry;
        if (ox < W && oy < H) {
            float sv = 0.f;
            if (yin) {
                if (!(j & 1)) {
                    int r0 = ry >> 1;
                    sv = g.w[0]*mid[r0][c] + g.w[2]*mid[r0+1][c] + g.w[4]*mid[r0+2][c]
                       + g.w[6]*mid[r0+3][c] + g.w[8]*mid[r0+4][c];
                } else {
                    int r0 = ((ry - 3) >> 1) + 2;
                    sv = g.w[1]*mid[r0][c] + g.w[3]*mid[r0+1][c]
                       + g.w[5]*mid[r0+2][c] + g.w[7]*mid[r0+3][c];
                }
            } else {
                #pragma unroll
                for (int k = 0; k < 9; ++k) {
                    int gy = ridx(oy - 4 + k, H);
                    if (!(gy & 1)) sv = fmaf(g.w[k], mid[(gy >> 1) - vy0][c], sv);
                }
            }
            lsum += fabsf(cur[c_off + (size_t)oy * W + ox] - sv);
        }
    }
    float tot = block_sum256(lsum);
    if (tid == 0) Pslot[local] = tot * invn;
}

// ---------------------------------------------------------------------------
// dev_k4f: 64x32-tile loss with fused-z staging (levels 2-4; dn may be LDS).
__device__ void dev_k4f(int local, const float* dnb,
                        const float* cur, float* Pslot,
                        int D, int H, int ntx, int nty, float invn, const GW& g)
{
    __shared__ float vt[20][72];
    __shared__ float mid[20][64];
    const int W = H, Dd = D >> 1, Hd = H >> 1, Wd = W >> 1, Md = Hd * Wd;
    const int s = local / (ntx*nty);
    const int rem = local - s*(ntx*nty);
    const int ty = rem / ntx, tx = rem - ty*ntx;
    const int x0 = tx*64, y0 = ty*32;
    const int b = s / D, z = s - b*D;
    const float* dn0 = dnb + (size_t)b * Dd * Md;
    const float* dn1 = dnb + (size_t)(1 - b) * Dd * Md;
    const int tid = threadIdx.x;
    const int vy0 = (y0 >> 1) - 2;

    for (int i = tid; i < 20*72; i += 256) {
        int rr = i / 72, cc = i - rr*72;
        int vy = vy0 + rr;
        int txx = x0 - 4 + cc;
        if (txx < 0) txx = -1 - txx;
        float v = 0.f;
        if (vy >= 0 && vy < Hd && txx < Wd) {
            size_t o = (size_t)vy * Wd + txx;
            float s0 = 0.f, s1 = 0.f;
            #pragma unroll
            for (int k = 0; k < 9; ++k) {
                int zk = ridx(z - 4 + k, D);
                if (!(zk & 1)) {
                    int j = zk >> 1;
                    s0 = fmaf(g.w[k], dn0[(size_t)j * Md + o], s0);
                    s1 = fmaf(g.w[k], dn1[(size_t)j * Md + o], s1);
                }
            }
            v = 8.f * (g.A*s0 + g.B*s1);
        }
        vt[rr][cc] = v;
    }
    __syncthreads();
    for (int i = tid; i < 20*64; i += 256) {
        int rr = i >> 6, c = i & 63;
        float sv = 0.f;
        #pragma unroll
        for (int k = 0; k < 9; ++k) sv = fmaf(g.w[k], vt[rr][c + k], sv);
        mid[rr][c] = sv;
    }
    __syncthreads();
    const bool yin = (y0 >= 4) && (y0 + 35 < H);
    const int c = tid & 63;
    const int ry_base = (tid >> 6) * 8;
    const int ox = x0 + c;
    const size_t c_off = (size_t)s * H * W;
    float lsum = 0.f;
    #pragma unroll
    for (int j = 0; j < 8; ++j) {
        int ry = ry_base + j;
        int oy = y0 + ry;
        if (ox < W && oy < H) {
            float sv = 0.f;
            if (yin) {
                if (!(j & 1)) {
                    int r0 = ry >> 1;
                    sv = g.w[0]*mid[r0][c] + g.w[2]*mid[r0+1][c] + g.w[4]*mid[r0+2][c]
                       + g.w[6]*mid[r0+3][c] + g.w[8]*mid[r0+4][c];
                } else {
                    int r0 = ((ry - 3) >> 1) + 2;
                    sv = g.w[1]*mid[r0][c] + g.w[3]*mid[r0+1][c]
                       + g.w[5]*mid[r0+2][c] + g.w[7]*mid[r0+3][c];
                }
            } else {
                #pragma unroll
                for (int k = 0; k < 9; ++k) {
                    int gy = ridx(oy - 4 + k, H);
                    if (!(gy & 1)) sv = fmaf(g.w[k], mid[(gy >> 1) - vy0][c], sv);
                }
            }
            lsum += fabsf(cur[c_off + (size_t)oy * W + ox] - sv);
        }
    }
    float tot = block_sum256(lsum);
    if (tid == 0) Pslot[local] = tot * invn;
}

// ------------------------------- fat kernels --------------------------------
// D3: k1s1 (256) || k3_0 (1024)
__global__ __launch_bounds__(256)
void kD3(const float* __restrict__ C1, float* __restrict__ Tl1,
         float* __restrict__ V0, GW g)
{
    int bid = (int)blockIdx.x;
    if (bid < 256) {
        int ty = bid & 3, slice = bid >> 2;
        dev_k1_slice(C1, Tl1, 0, ty*16, slice, 128, 128, 64, 64, g);
    } else {
        long i = (long)(bid - 256)*256 + threadIdx.x;
        dev_k3_elem(i, (const float4*)C1, (float4*)V0, 64, 32, 4096, g);
    }
}

// D4: k2s1 (64) || k4-L0 (1536, 64x64)
__global__ __launch_bounds__(256)
void kD4(const float* __restrict__ Tl1, float* __restrict__ C2,
         const float* __restrict__ V0, const __hip_bfloat16* __restrict__ DIFF,
         const float* __restrict__ in, const float* __restrict__ tg,
         int use_diff, float* __restrict__ P, GW g)
{
    int bid = (int)blockIdx.x;
    if (bid < 64) {
        long i = (long)bid*256 + threadIdx.x;
        dev_k2_elem(i, (const float4*)Tl1, (float4*)C2, 32, 16, 1024, g);
    } else {
        dev_k4v064(bid - 64, V0, DIFF, in, tg, use_diff, P, g);
    }
}

// D5: k1s2 (64) || k4-L1 (256, 64x64, fused-z dn=C2, cur=C1)
__global__ __launch_bounds__(256)
void kD5(const float* __restrict__ C2, float* __restrict__ Tl2,
         const float* __restrict__ C1, float* __restrict__ P, GW g)
{
    int bid = (int)blockIdx.x;
    if (bid < 64) {
        int ty = bid & 1, slice = bid >> 1;
        dev_k1_slice(C2, Tl2, 0, ty*16, slice, 64, 64, 32, 32, g);
    } else {
        dev_k4f64(bid - 64, C2, C1, P + 2560, 32, 128, 2, 2, 1.f / 1048576.f, g);
    }
}

// D7: k1s3 (16) || k4-L2 (64, fused-z dn=C3, cur=C2)
__global__ __launch_bounds__(256)
void kD7(const float* __restrict__ C3, float* __restrict__ Tl3,
         const float* __restrict__ C2, float* __restrict__ P, GW g)
{
    int bid = (int)blockIdx.x;
    if (bid < 16) {
        dev_k1_slice(C3, Tl3, 0, 0, bid, 32, 32, 16, 16, g);
    } else {
        dev_k4f(bid - 16, C3, C2, P + 2816, 16, 64, 1, 2, 1.f / 131072.f, g);
    }
}

// ---------------------------------------------------------------------------
// D8 tailpar: 24 parallel blocks, each redundantly builds the tail chain in LDS.
// Blocks 0..15: L3 loss (dn=sC4 LDS, cur=C3 global).
// Blocks 16..23: + sTl4, sC5; L4 loss (dn=sC5 LDS, cur=sC4 LDS).
__global__ __launch_bounds__(256)
void tailpar(const float* __restrict__ Tl3g, const float* __restrict__ C3,
             float* __restrict__ P, GW g)
{
    __shared__ float sTl3[4096];   // (2,8,16,16)
    __shared__ float sC4[2048];    // (2,4,16,16)
    __shared__ float sTl4[512];    // (2,4,8,8)
    __shared__ float sC5[256];     // (2,2,8,8)
    const int tid = threadIdx.x;
    const int bid = (int)blockIdx.x;
    for (int i = tid; i < 4096; i += 256) sTl3[i] = Tl3g[i];
    __syncthreads();
    for (int i = tid; i < 2048; i += 256) {
        int slice = i >> 8, yx = i & 255;
        int b = slice >> 2, zc = slice & 3;
        float s0 = 0.f, s1 = 0.f;
        #pragma unroll
        for (int k = 0; k < 9; ++k) {
            int zk = ridx(2*zc - 4 + k, 8);
            s0 = fmaf(g.w[k], sTl3[zk*256 + yx], s0);
            s1 = fmaf(g.w[k], sTl3[(8 + zk)*256 + yx], s1);
        }
        sC4[i] = (b == 0) ? (g.A*s0 + g.B*s1) : (g.B*s0 + g.A*s1);
    }
    __syncthreads();
    if (bid < 16) {
        dev_k4f(bid, sC4, C3, P + 2880, 8, 32, 1, 1, 1.f / 16384.f, g);
    } else {
        for (int i = tid; i < 512; i += 256) {
            int slice = i >> 6, y = (i >> 3) & 7, x = i & 7;
            float s = 0.f;
            for (int ky = 0; ky < 9; ++ky) {
                int gy = ridx(2*y - 4 + ky, 16);
                float rs = 0.f;
                #pragma unroll
                for (int kx = 0; kx < 9; ++kx) {
                    int gx = ridx(2*x - 4 + kx, 16);
                    rs = fmaf(g.w[kx], sC4[slice*256 + gy*16 + gx], rs);
                }
                s = fmaf(g.w[ky], rs, s);
            }
            sTl4[i] = s;
        }
        __syncthreads();
        for (int i = tid; i < 256; i += 256) {
            int slice = i >> 6, yx = i & 63;
            int b = slice >> 1, zc = slice & 1;
            float s0 = 0.f, s1 = 0.f;
            #pragma unroll
            for (int k = 0; k < 9; ++k) {
                int zk = ridx(2*zc - 4 + k, 4);
                s0 = fmaf(g.w[k], sTl4[zk*64 + yx], s0);
                s1 = fmaf(g.w[k], sTl4[(4 + zk)*64 + yx], s1);
            }
            sC5[i] = (b == 0) ? (g.A*s0 + g.B*s1) : (g.B*s0 + g.A*s1);
        }
        __syncthreads();
        dev_k4f(bid - 16, sC5, sC4, P + 2896, 4, 16, 1, 1, 1.f / 2048.f, g);
    }
}

// ---------------------------------------------------------------------------
__global__ __launch_bounds__(1024)
void kreduce(const float* __restrict__ P, int n, float* __restrict__ out)
{
    float s = 0.f;
    for (int i = threadIdx.x; i < n; i += 1024) s += P[i];
    float t = block_sum1024(s);
    if (threadIdx.x == 0) out[0] = t;
}

// ---------------------------------------------------------------------------
extern "C" void kernel_launch(void* const* d_in, const int* in_sizes, int n_in,
                              void* d_out, int out_size, void* d_ws, size_t ws_size,
                              hipStream_t stream)
{
    const float* in = (const float*)d_in[0];
    const float* tg = (const float*)d_in[1];
    float* out = (float*)d_out;

    GW g;
    {
        double u[9], S = 0.0;
        for (int k = 0; k < 9; ++k) { double d = k - 4; u[k] = exp(-0.5 * d * d); S += u[k]; }
        for (int k = 0; k < 9; ++k) g.w[k] = (float)(u[k] / S);
        g.A = (float)((2.0*u[0] + u[1] + u[3] + u[4]) / S);  // batch(2) reflect self-weight
        g.B = (float)((u[1] + 2.0*u[2] + u[3]) / S);         // cross-weight
    }

    // workspace layout (floats)
    float* T1  = (float*)d_ws;             // 2*64*128*128 = 2097152
    float* C1  = T1  + 2097152;            // 2*32*128*128 = 1048576
    float* C2  = C1  + 1048576;            // 2*16*64*64   = 131072
    float* C3  = C2  + 131072;             // 2*8*32*32    = 16384
    float* Tl1 = C3  + 16384;              // 2*32*64*64   = 262144
    float* Tl2 = Tl1 + 262144;             // 2*16*32*32   = 32768
    float* Tl3 = Tl2 + 32768;              // 2*8*16*16    = 4096
    float* V0  = Tl3 + 4096;               // 2*64*128*128 = 2097152
    float* P   = V0  + 2097152;            // 2904 partials (cap 4096)
    float* wend = P + 4096;
    __hip_bfloat16* DIFF = (__hip_bfloat16*)wend;
    const size_t base_bytes = (size_t)((char*)wend - (char*)d_ws);
    const size_t diff_bytes = (size_t)2 * 64 * 256 * 256 * sizeof(__hip_bfloat16);
    const int use_diff = (ws_size >= base_bytes + diff_bytes) ? 1 : 0;

    dim3 blk(256);

    // D1: level-0 WH-down of diff (+ bf16 DIFF x<132, + x>=132 partials)
    if (use_diff) k1l0<true ><<<dim3(2,8,128), blk, 0, stream>>>(in, tg, T1, DIFF, P, g);
    else          k1l0<false><<<dim3(2,8,128), blk, 0, stream>>>(in, tg, T1, nullptr, P, g);

    // D2: k2s0: T1 -> C1  (D=64, Dd=32, M4=4096)
    k2s<<<dim3(512), blk, 0, stream>>>(T1, C1, 64, 32, 4096, g);

    // D3: k1s1 (C1->Tl1, 256) || k3_0 (C1->V0, 1024)
    kD3<<<dim3(1280), blk, 0, stream>>>(C1, Tl1, V0, g);

    // D4: k2s1 (Tl1->C2, 64) || k4-L0 (1536, 64x64)
    kD4<<<dim3(1600), blk, 0, stream>>>(Tl1, C2, V0, use_diff ? DIFF : nullptr,
                                        in, tg, use_diff, P, g);

    // D5: k1s2 (C2->Tl2, 64) || k4-L1 (256, 64x64)
    kD5<<<dim3(320), blk, 0, stream>>>(C2, Tl2, C1, P, g);

    // D6: k2s2: Tl2 -> C3  (D=16, Dd=8, M4=256)
    k2s<<<dim3(8), blk, 0, stream>>>(Tl2, C3, 16, 8, 256, g);

    // D7: k1s3 (C3->Tl3, 16) || k4-L2 (64)
    kD7<<<dim3(80), blk, 0, stream>>>(C3, Tl3, C2, P, g);

    // D8: tailpar (L3: 16 blocks, L4: 8 blocks)
    tailpar<<<dim3(24), blk, 0, stream>>>(Tl3, C3, P, g);

    // D9: final reduce over 2904 partials
    kreduce<<<dim3(1), dim3(1024), 0, stream>>>(P, 2904, out);
}

// Round 16
// 97.882 us; speedup vs baseline: 1.1074x; 1.1074x over previous
//
#include <hip/hip_runtime.h>
#include <hip/hip_bf16.h>
#include <math.h>

// Laplacian-pyramid L1 loss, (2,1,64,256,256), 5 levels, sigma=1 (9-tap), scipy-reflect.
// loss = sum_l mean |lap_pyramid(input-target)[l]| (linearity of the pyramid).
// REVERT to round-14 structure (best measured: 99.45us). r15's 64x64 tiles
// regressed: per-device-function __shared__ arrays SUM (not union) in fat
// kernels -> 51KB LDS -> 3 blocks/CU -> lost latency hiding. 64x32 @ 11.3KB
// is the sweet spot.
// 9 plain launches; losses packed into ladder launches; no cross-block sync
// (r5/r7), no serial single-block kernels (r3/r12).
//  D1 k1l0(+bf16 DIFF x<132 + x>=132 partials)
//  D2 k2s0: T1->C1 (512)
//  D3 FAT[k1s1 (256) || k3_0: C1->V0 (1024)]
//  D4 FAT[k2s1 (64) || k4-L0 (3072, V0+DIFF)]
//  D5 FAT[k1s2 (64) || k4-L1 (512, fused-z dn=C2, cur=C1)]
//  D6 k2s2 (8)
//  D7 FAT[k1s3 (16) || k4-L2 (64, fused-z dn=C3, cur=C2)]
//  D8 tailpar (24): LDS chain Tl3->C4(->Tl4->C5); L3+L4 losses via dev_k4f
//  D9 kreduce (4696 partials)

struct GW { float w[9]; float A, B; };

__device__ __forceinline__ int ridx(int p, int n) {
    // scipy 'reflect' (symmetric) for power-of-two n; valid for p >= -2n
    int m = 2 * n;
    int q = (p + m) & (m - 1);
    return (q < n) ? q : (m - 1 - q);
}

__device__ __forceinline__ float block_sum256(float v) {
    #pragma unroll
    for (int off = 32; off > 0; off >>= 1) v += __shfl_down(v, off, 64);
    __shared__ float wp[4];
    int tid = threadIdx.x;
    if ((tid & 63) == 0) wp[tid >> 6] = v;
    __syncthreads();
    return wp[0] + wp[1] + wp[2] + wp[3];
}

__device__ __forceinline__ float block_sum1024(float v) {
    #pragma unroll
    for (int off = 32; off > 0; off >>= 1) v += __shfl_down(v, off, 64);
    __shared__ float wp[16];
    int tid = threadIdx.x;
    if ((tid & 63) == 0) wp[tid >> 6] = v;
    __syncthreads();
    float t = 0.f;
    if (tid == 0) {
        #pragma unroll
        for (int w = 0; w < 16; ++w) t += wp[w];
    }
    return t;
}

// ---------------------------------------------------------------------------
// k1l0: level-0 fused W+H gaussian of (in - tg) -> T1 (even y,x).
// Also: bf16 DIFF for x<132, and the x>=132 |diff| sums as partials P[0..1024).
template<bool WDIFF>
__global__ __launch_bounds__(256)
void k1l0(const float* __restrict__ in, const float* __restrict__ tg,
          float* __restrict__ T1, __hip_bfloat16* __restrict__ DIFF,
          float* __restrict__ P, GW g)
{
    const int H = 256, W = 256, Wd = 128;
    const int x0d = blockIdx.x * 64, y0d = blockIdx.y * 16, slice = blockIdx.z;
    __shared__ float raw[40][136];
    __shared__ float mid[40][64];
    const size_t in_off  = (size_t)slice * H * W;
    const size_t out_off = (size_t)slice * 128 * 128;
    const int tid = threadIdx.x;
    const int gy0 = 2*y0d - 4, gx0 = 2*x0d - 4;
    for (int i = tid; i < 40*32; i += 256) {
        int rr = i >> 5, c4 = (i & 31) + 1;
        int gy = ridx(gy0 + rr, H);
        size_t base = in_off + (size_t)gy * W + gx0 + 4*c4;
        float4 v = *(const float4*)(in + base);
        float4 b = *(const float4*)(tg + base);
        v.x -= b.x; v.y -= b.y; v.z -= b.z; v.w -= b.w;
        *(float4*)&raw[rr][4*c4] = v;
    }
    for (int i = tid; i < 40*8; i += 256) {
        int rr = i >> 3, j = i & 7;
        int cc = (j < 4) ? j : (128 + j);
        int gy = ridx(gy0 + rr, H);
        int gx = ridx(gx0 + cc, W);
        size_t idx = in_off + (size_t)gy * W + gx;
        raw[rr][cc] = in[idx] - tg[idx];
    }
    __syncthreads();
    if (WDIFF) {
        if (blockIdx.x == 0) {
            for (int i = tid; i < 32*128; i += 256) {
                int r = i >> 7, c = i & 127;
                DIFF[in_off + (size_t)(2*y0d + r) * W + c] =
                    __float2bfloat16(raw[4 + r][4 + c]);
            }
        } else {
            for (int i = tid; i < 32*4; i += 256) {
                int r = i >> 2, c = i & 3;
                DIFF[in_off + (size_t)(2*y0d + r) * W + 128 + c] =
                    __float2bfloat16(raw[4 + r][4 + c]);
            }
        }
    }
    if (blockIdx.x == 1) {
        // x >= 132 loss contribution (up == 0 there)
        float lsum = 0.f;
        for (int i = tid; i < 32*124; i += 256) {
            int r = i / 124, c = i - r*124;
            lsum += fabsf(raw[4 + r][8 + c]);
        }
        float tot = block_sum256(lsum);
        if (tid == 0)
            P[blockIdx.y + 8*blockIdx.z] = tot * (1.f / 8388608.f);
    }
    for (int i = tid; i < 40*64; i += 256) {
        int rr = i >> 6, c = i & 63;
        float s = 0.f;
        #pragma unroll
        for (int k = 0; k < 9; ++k) s = fmaf(g.w[k], raw[rr][2*c + k], s);
        mid[rr][c] = s;
    }
    __syncthreads();
    {
        int r = tid >> 6, c = tid & 63;
        int ox = x0d + c;
        #pragma unroll
        for (int j = 0; j < 4; ++j) {
            int oy = y0d + r*4 + j;
            int rb = 2*(r*4 + j);
            float s = 0.f;
            #pragma unroll
            for (int k = 0; k < 9; ++k) s = fmaf(g.w[k], mid[rb + k][c], s);
            T1[out_off + (size_t)oy * Wd + ox] = s;
        }
    }
}

// ---------------------------------------------------------------------------
// dev_k2_elem: D-axis gaussian + batch(2) reflect mix at even z. One float4/elem.
__device__ void dev_k2_elem(long i, const float4* __restrict__ T, float4* __restrict__ O,
                            int D, int Dd, int M4, const GW& g)
{
    if (i >= (long)Dd * M4) return;
    int zd = (int)(i / M4);
    int q  = (int)(i - (long)zd * M4);
    float4 s0 = {0,0,0,0}, s1 = {0,0,0,0};
    #pragma unroll
    for (int k = 0; k < 9; ++k) {
        int zp = 2*zd - 4 + k;
        int zk = (zp >= 0 && zp < D) ? zp : ridx(zp, D);
        float4 a = T[(size_t)zk * M4 + q];
        float4 b = T[(size_t)(D + zk) * M4 + q];
        s0.x = fmaf(g.w[k], a.x, s0.x); s0.y = fmaf(g.w[k], a.y, s0.y);
        s0.z = fmaf(g.w[k], a.z, s0.z); s0.w = fmaf(g.w[k], a.w, s0.w);
        s1.x = fmaf(g.w[k], b.x, s1.x); s1.y = fmaf(g.w[k], b.y, s1.y);
        s1.z = fmaf(g.w[k], b.z, s1.z); s1.w = fmaf(g.w[k], b.w, s1.w);
    }
    float4 o0, o1;
    o0.x = g.A*s0.x + g.B*s1.x; o0.y = g.A*s0.y + g.B*s1.y;
    o0.z = g.A*s0.z + g.B*s1.z; o0.w = g.A*s0.w + g.B*s1.w;
    o1.x = g.B*s0.x + g.A*s1.x; o1.y = g.B*s0.y + g.A*s1.y;
    o1.z = g.B*s0.z + g.A*s1.z; o1.w = g.B*s0.w + g.A*s1.w;
    O[(size_t)zd * M4 + q] = o0;
    O[(size_t)(Dd + zd) * M4 + q] = o1;
}

__global__ __launch_bounds__(256)
void k2s(const float* __restrict__ Tin, float* __restrict__ Cout,
         int D, int Dd, int M4, GW g)
{
    long i = (long)blockIdx.x * 256 + threadIdx.x;
    dev_k2_elem(i, (const float4*)Tin, (float4*)Cout, D, Dd, M4, g);
}

// ---------------------------------------------------------------------------
// dev_k1_slice: fused W+H gaussian on one (H,W) slice, even (y,x) -> (Hd,Wd).
__device__ void dev_k1_slice(const float* __restrict__ inA, float* __restrict__ out,
                             int x0d, int y0d, int slice, int H, int W, int Hd, int Wd,
                             const GW& g)
{
    __shared__ float raw[40][136];
    __shared__ float mid[40][64];
    const size_t in_off  = (size_t)slice * H * W;
    const size_t out_off = (size_t)slice * Hd * Wd;
    const int tid = threadIdx.x;
    const int gy0 = 2*y0d - 4, gx0 = 2*x0d - 4;
    if (2*x0d + 127 < W) {
        for (int i = tid; i < 40*32; i += 256) {
            int rr = i >> 5, c4 = (i & 31) + 1;
            int gy = ridx(gy0 + rr, H);
            *(float4*)&raw[rr][4*c4] =
                *(const float4*)(inA + in_off + (size_t)gy * W + gx0 + 4*c4);
        }
        for (int i = tid; i < 40*8; i += 256) {
            int rr = i >> 3, j = i & 7;
            int cc = (j < 4) ? j : (128 + j);
            int gy = ridx(gy0 + rr, H), gx = ridx(gx0 + cc, W);
            raw[rr][cc] = inA[in_off + (size_t)gy * W + gx];
        }
    } else {
        for (int i = tid; i < 40*136; i += 256) {
            int rr = i / 136, cc = i - rr*136;
            int gy = ridx(gy0 + rr, H), gx = ridx(gx0 + cc, W);
            raw[rr][cc] = inA[in_off + (size_t)gy * W + gx];
        }
    }
    __syncthreads();
    for (int i = tid; i < 40*64; i += 256) {
        int rr = i >> 6, c = i & 63;
        float s = 0.f;
        #pragma unroll
        for (int k = 0; k < 9; ++k) s = fmaf(g.w[k], raw[rr][2*c + k], s);
        mid[rr][c] = s;
    }
    __syncthreads();
    {
        int r = tid >> 6, c = tid & 63;
        int ox = x0d + c;
        #pragma unroll
        for (int j = 0; j < 4; ++j) {
            int oy = y0d + r*4 + j;
            if (oy < Hd && ox < Wd) {
                int rb = 2*(r*4 + j);
                float s = 0.f;
                #pragma unroll
                for (int k = 0; k < 9; ++k) s = fmaf(g.w[k], mid[rb + k][c], s);
                out[out_off + (size_t)oy * Wd + ox] = s;
            }
        }
    }
}

// ---------------------------------------------------------------------------
// dev_k3_elem: D-filter of zero-stuffed dn + batch mix (upsample D/batch), x8.
__device__ void dev_k3_elem(long i, const float4* __restrict__ Dn, float4* __restrict__ O,
                            int D, int Dd, int M4, const GW& g)
{
    if (i >= (long)D * M4) return;
    int z = (int)(i / M4);
    int q = (int)(i - (long)z * M4);
    float4 s0 = {0,0,0,0}, s1 = {0,0,0,0};
    auto f4 = [](float4& a, float w, const float4 b) {
        a.x = fmaf(w, b.x, a.x); a.y = fmaf(w, b.y, a.y);
        a.z = fmaf(w, b.z, a.z); a.w = fmaf(w, b.w, a.w);
    };
    if (z >= 4 && z + 4 < D) {
        if ((z & 1) == 0) {
            int base = (z >> 1) - 2;
            #pragma unroll
            for (int kk = 0; kk < 5; ++kk) {
                f4(s0, g.w[2*kk], Dn[(size_t)(base + kk) * M4 + q]);
                f4(s1, g.w[2*kk], Dn[(size_t)(Dd + base + kk) * M4 + q]);
            }
        } else {
            int base = (z - 3) >> 1;
            #pragma unroll
            for (int kk = 0; kk < 4; ++kk) {
                f4(s0, g.w[2*kk+1], Dn[(size_t)(base + kk) * M4 + q]);
                f4(s1, g.w[2*kk+1], Dn[(size_t)(Dd + base + kk) * M4 + q]);
            }
        }
    } else {
        #pragma unroll
        for (int k = 0; k < 9; ++k) {
            int zk = ridx(z - 4 + k, D);
            if (!(zk & 1)) {
                int j = zk >> 1;
                f4(s0, g.w[k], Dn[(size_t)j * M4 + q]);
                f4(s1, g.w[k], Dn[(size_t)(Dd + j) * M4 + q]);
            }
        }
    }
    float4 o0, o1;
    o0.x = 8.f*(g.A*s0.x + g.B*s1.x); o0.y = 8.f*(g.A*s0.y + g.B*s1.y);
    o0.z = 8.f*(g.A*s0.z + g.B*s1.z); o0.w = 8.f*(g.A*s0.w + g.B*s1.w);
    o1.x = 8.f*(g.B*s0.x + g.A*s1.x); o1.y = 8.f*(g.B*s0.y + g.A*s1.y);
    o1.z = 8.f*(g.B*s0.z + g.A*s1.z); o1.w = 8.f*(g.B*s0.w + g.A*s1.w);
    O[(size_t)z * M4 + q] = o0;
    O[(size_t)(D + z) * M4 + q] = o1;
}

// ---------------------------------------------------------------------------
// dev_k4v0: level-0 loss tile from materialized V0 + bf16 DIFF (r10 proven).
__device__ void dev_k4v0(int local, const float* __restrict__ V0,
                         const __hip_bfloat16* __restrict__ DIFF,
                         const float* __restrict__ in, const float* __restrict__ tg,
                         int use_diff, float* __restrict__ P, const GW& g)
{
    __shared__ float vt[20][72];
    __shared__ float mid[20][64];
    const int H = 256, W = 256, Hd = 128, Wd = 128, Md = 128*128;
    const int s = local / 24;
    const int rem = local - s*24;
    const int ty = rem / 3, tx = rem - ty*3;
    const int x0 = tx*64, y0 = ty*32;
    const int tid = threadIdx.x;
    const int vy0 = (y0 >> 1) - 2;
    const size_t v_off = (size_t)s * Md;
    for (int i = tid; i < 20*72; i += 256) {
        int rr = i / 72, cc = i - rr*72;
        int vy = vy0 + rr;
        int txx = x0 - 4 + cc;
        if (txx < 0) txx = -1 - txx;
        float v = 0.f;
        if (vy >= 0 && vy < Hd && txx < Wd) v = V0[v_off + (size_t)vy * Wd + txx];
        vt[rr][cc] = v;
    }
    __syncthreads();
    for (int i = tid; i < 20*64; i += 256) {
        int rr = i >> 6, c = i & 63;
        float sv = 0.f;
        #pragma unroll
        for (int k = 0; k < 9; ++k) sv = fmaf(g.w[k], vt[rr][c + k], sv);
        mid[rr][c] = sv;
    }
    __syncthreads();
    const bool yin = (y0 >= 4) && (y0 + 35 < H);
    const int c = tid & 63;
    const int ry_base = (tid >> 6) * 8;
    const int ox = x0 + c;
    const size_t c_off = (size_t)s * H * W;
    float lsum = 0.f;
    #pragma unroll
    for (int j = 0; j < 8; ++j) {
        int ry = ry_base + j;
        int oy = y0 + ry;
        if (ox < 132 && oy < H) {
            float sv = 0.f;
            if (yin) {
                if (!(j & 1)) {
                    int r0 = ry >> 1;
                    sv = g.w[0]*mid[r0][c] + g.w[2]*mid[r0+1][c] + g.w[4]*mid[r0+2][c]
                       + g.w[6]*mid[r0+3][c] + g.w[8]*mid[r0+4][c];
                } else {
                    int r0 = ((ry - 3) >> 1) + 2;
                    sv = g.w[1]*mid[r0][c] + g.w[3]*mid[r0+1][c]
                       + g.w[5]*mid[r0+2][c] + g.w[7]*mid[r0+3][c];
                }
            } else {
                #pragma unroll
                for (int k = 0; k < 9; ++k) {
                    int gy = ridx(oy - 4 + k, H);
                    if (!(gy & 1)) sv = fmaf(g.w[k], mid[(gy >> 1) - vy0][c], sv);
                }
            }
            size_t idx = c_off + (size_t)oy * W + ox;
            float cv = use_diff ? __bfloat162float(DIFF[idx]) : (in[idx] - tg[idx]);
            lsum += fabsf(cv - sv);
        }
    }
    float tot = block_sum256(lsum);
    if (tid == 0) P[1024 + local] = tot * (1.f / 8388608.f);
}

// ---------------------------------------------------------------------------
// dev_k4f: loss tile with fused-z staging from dn (global OR LDS pointer).
__device__ void dev_k4f(int local, const float* dnb,
                        const float* cur, float* Pslot,
                        int D, int H, int ntx, int nty, float invn, const GW& g)
{
    __shared__ float vt[20][72];
    __shared__ float mid[20][64];
    const int W = H, Dd = D >> 1, Hd = H >> 1, Wd = W >> 1, Md = Hd * Wd;
    const int s = local / (ntx*nty);
    const int rem = local - s*(ntx*nty);
    const int ty = rem / ntx, tx = rem - ty*ntx;
    const int x0 = tx*64, y0 = ty*32;
    const int b = s / D, z = s - b*D;
    const float* dn0 = dnb + (size_t)b * Dd * Md;
    const float* dn1 = dnb + (size_t)(1 - b) * Dd * Md;
    const int tid = threadIdx.x;
    const int vy0 = (y0 >> 1) - 2;

    const bool zin = (z >= 4) && (z + 4 < D);
    if (zin && !(z & 1)) {
        const int j0 = (z >> 1) - 2;
        for (int i = tid; i < 20*72; i += 256) {
            int rr = i / 72, cc = i - rr*72;
            int vy = vy0 + rr;
            int txx = x0 - 4 + cc;
            if (txx < 0) txx = -1 - txx;
            float v = 0.f;
            if (vy >= 0 && vy < Hd && txx < Wd) {
                size_t o = (size_t)vy * Wd + txx;
                float s0 = 0.f, s1 = 0.f;
                #pragma unroll
                for (int t = 0; t < 5; ++t) {
                    s0 = fmaf(g.w[2*t], dn0[(size_t)(j0 + t) * Md + o], s0);
                    s1 = fmaf(g.w[2*t], dn1[(size_t)(j0 + t) * Md + o], s1);
                }
                v = 8.f * (g.A*s0 + g.B*s1);
            }
            vt[rr][cc] = v;
        }
    } else if (zin) {
        const int j0 = (z - 3) >> 1;
        for (int i = tid; i < 20*72; i += 256) {
            int rr = i / 72, cc = i - rr*72;
            int vy = vy0 + rr;
            int txx = x0 - 4 + cc;
            if (txx < 0) txx = -1 - txx;
            float v = 0.f;
            if (vy >= 0 && vy < Hd && txx < Wd) {
                size_t o = (size_t)vy * Wd + txx;
                float s0 = 0.f, s1 = 0.f;
                #pragma unroll
                for (int t = 0; t < 4; ++t) {
                    s0 = fmaf(g.w[2*t+1], dn0[(size_t)(j0 + t) * Md + o], s0);
                    s1 = fmaf(g.w[2*t+1], dn1[(size_t)(j0 + t) * Md + o], s1);
                }
                v = 8.f * (g.A*s0 + g.B*s1);
            }
            vt[rr][cc] = v;
        }
    } else {
        for (int i = tid; i < 20*72; i += 256) {
            int rr = i / 72, cc = i - rr*72;
            int vy = vy0 + rr;
            int txx = x0 - 4 + cc;
            if (txx < 0) txx = -1 - txx;
            float v = 0.f;
            if (vy >= 0 && vy < Hd && txx < Wd) {
                size_t o = (size_t)vy * Wd + txx;
                float s0 = 0.f, s1 = 0.f;
                #pragma unroll
                for (int k = 0; k < 9; ++k) {
                    int zk = ridx(z - 4 + k, D);
                    if (!(zk & 1)) {
                        int j = zk >> 1;
                        s0 = fmaf(g.w[k], dn0[(size_t)j * Md + o], s0);
                        s1 = fmaf(g.w[k], dn1[(size_t)j * Md + o], s1);
                    }
                }
                v = 8.f * (g.A*s0 + g.B*s1);
            }
            vt[rr][cc] = v;
        }
    }
    __syncthreads();
    for (int i = tid; i < 20*64; i += 256) {
        int rr = i >> 6, c = i & 63;
        float sv = 0.f;
        #pragma unroll
        for (int k = 0; k < 9; ++k) sv = fmaf(g.w[k], vt[rr][c + k], sv);
        mid[rr][c] = sv;
    }
    __syncthreads();
    const bool yin = (y0 >= 4) && (y0 + 35 < H);
    const int c = tid & 63;
    const int ry_base = (tid >> 6) * 8;
    const int ox = x0 + c;
    const size_t c_off = (size_t)s * H * W;
    float lsum = 0.f;
    #pragma unroll
    for (int j = 0; j < 8; ++j) {
        int ry = ry_base + j;
        int oy = y0 + ry;
        if (ox < W && oy < H) {
            float sv = 0.f;
            if (yin) {
                if (!(j & 1)) {
                    int r0 = ry >> 1;
                    sv = g.w[0]*mid[r0][c] + g.w[2]*mid[r0+1][c] + g.w[4]*mid[r0+2][c]
                       + g.w[6]*mid[r0+3][c] + g.w[8]*mid[r0+4][c];
                } else {
                    int r0 = ((ry - 3) >> 1) + 2;
                    sv = g.w[1]*mid[r0][c] + g.w[3]*mid[r0+1][c]
                       + g.w[5]*mid[r0+2][c] + g.w[7]*mid[r0+3][c];
                }
            } else {
                #pragma unroll
                for (int k = 0; k < 9; ++k) {
                    int gy = ridx(oy - 4 + k, H);
                    if (!(gy & 1)) sv = fmaf(g.w[k], mid[(gy >> 1) - vy0][c], sv);
                }
            }
            lsum += fabsf(cur[c_off + (size_t)oy * W + ox] - sv);
        }
    }
    float tot = block_sum256(lsum);
    if (tid == 0) Pslot[local] = tot * invn;
}

// ------------------------------- fat kernels --------------------------------
// D3: k1s1 (256) || k3_0 (1024)
__global__ __launch_bounds__(256)
void kD3(const float* __restrict__ C1, float* __restrict__ Tl1,
         float* __restrict__ V0, GW g)
{
    int bid = (int)blockIdx.x;
    if (bid < 256) {
        int ty = bid & 3, slice = bid >> 2;
        dev_k1_slice(C1, Tl1, 0, ty*16, slice, 128, 128, 64, 64, g);
    } else {
        long i = (long)(bid - 256)*256 + threadIdx.x;
        dev_k3_elem(i, (const float4*)C1, (float4*)V0, 64, 32, 4096, g);
    }
}

// D4: k2s1 (64) || k4-L0 (3072)
__global__ __launch_bounds__(256)
void kD4(const float* __restrict__ Tl1, float* __restrict__ C2,
         const float* __restrict__ V0, const __hip_bfloat16* __restrict__ DIFF,
         const float* __restrict__ in, const float* __restrict__ tg,
         int use_diff, float* __restrict__ P, GW g)
{
    int bid = (int)blockIdx.x;
    if (bid < 64) {
        long i = (long)bid*256 + threadIdx.x;
        dev_k2_elem(i, (const float4*)Tl1, (float4*)C2, 32, 16, 1024, g);
    } else {
        dev_k4v0(bid - 64, V0, DIFF, in, tg, use_diff, P, g);
    }
}

// D5: k1s2 (64) || k4-L1 (512, fused-z dn=C2, cur=C1)
__global__ __launch_bounds__(256)
void kD5(const float* __restrict__ C2, float* __restrict__ Tl2,
         const float* __restrict__ C1, float* __restrict__ P, GW g)
{
    int bid = (int)blockIdx.x;
    if (bid < 64) {
        int ty = bid & 1, slice = bid >> 1;
        dev_k1_slice(C2, Tl2, 0, ty*16, slice, 64, 64, 32, 32, g);
    } else {
        dev_k4f(bid - 64, C2, C1, P + 4096, 32, 128, 2, 4, 1.f / 1048576.f, g);
    }
}

// D7: k1s3 (16) || k4-L2 (64, fused-z dn=C3, cur=C2)
__global__ __launch_bounds__(256)
void kD7(const float* __restrict__ C3, float* __restrict__ Tl3,
         const float* __restrict__ C2, float* __restrict__ P, GW g)
{
    int bid = (int)blockIdx.x;
    if (bid < 16) {
        dev_k1_slice(C3, Tl3, 0, 0, bid, 32, 32, 16, 16, g);
    } else {
        dev_k4f(bid - 16, C3, C2, P + 4608, 16, 64, 1, 2, 1.f / 131072.f, g);
    }
}

// ---------------------------------------------------------------------------
// D8 tailpar: 24 parallel blocks, each redundantly builds the tail chain in LDS.
// Blocks 0..15: L3 loss (dn=sC4 LDS, cur=C3 global).
// Blocks 16..23: + sTl4, sC5; L4 loss (dn=sC5 LDS, cur=sC4 LDS).
__global__ __launch_bounds__(256)
void tailpar(const float* __restrict__ Tl3g, const float* __restrict__ C3,
             float* __restrict__ P, GW g)
{
    __shared__ float sTl3[4096];   // (2,8,16,16)
    __shared__ float sC4[2048];    // (2,4,16,16)
    __shared__ float sTl4[512];    // (2,4,8,8)
    __shared__ float sC5[256];     // (2,2,8,8)
    const int tid = threadIdx.x;
    const int bid = (int)blockIdx.x;
    for (int i = tid; i < 4096; i += 256) sTl3[i] = Tl3g[i];
    __syncthreads();
    for (int i = tid; i < 2048; i += 256) {
        int slice = i >> 8, yx = i & 255;
        int b = slice >> 2, zc = slice & 3;
        float s0 = 0.f, s1 = 0.f;
        #pragma unroll
        for (int k = 0; k < 9; ++k) {
            int zk = ridx(2*zc - 4 + k, 8);
            s0 = fmaf(g.w[k], sTl3[zk*256 + yx], s0);
            s1 = fmaf(g.w[k], sTl3[(8 + zk)*256 + yx], s1);
        }
        sC4[i] = (b == 0) ? (g.A*s0 + g.B*s1) : (g.B*s0 + g.A*s1);
    }
    __syncthreads();
    if (bid < 16) {
        dev_k4f(bid, sC4, C3, P + 4672, 8, 32, 1, 1, 1.f / 16384.f, g);
    } else {
        for (int i = tid; i < 512; i += 256) {
            int slice = i >> 6, y = (i >> 3) & 7, x = i & 7;
            float s = 0.f;
            for (int ky = 0; ky < 9; ++ky) {
                int gy = ridx(2*y - 4 + ky, 16);
                float rs = 0.f;
                #pragma unroll
                for (int kx = 0; kx < 9; ++kx) {
                    int gx = ridx(2*x - 4 + kx, 16);
                    rs = fmaf(g.w[kx], sC4[slice*256 + gy*16 + gx], rs);
                }
                s = fmaf(g.w[ky], rs, s);
            }
            sTl4[i] = s;
        }
        __syncthreads();
        for (int i = tid; i < 256; i += 256) {
            int slice = i >> 6, yx = i & 63;
            int b = slice >> 1, zc = slice & 1;
            float s0 = 0.f, s1 = 0.f;
            #pragma unroll
            for (int k = 0; k < 9; ++k) {
                int zk = ridx(2*zc - 4 + k, 4);
                s0 = fmaf(g.w[k], sTl4[zk*64 + yx], s0);
                s1 = fmaf(g.w[k], sTl4[(4 + zk)*64 + yx], s1);
            }
            sC5[i] = (b == 0) ? (g.A*s0 + g.B*s1) : (g.B*s0 + g.A*s1);
        }
        __syncthreads();
        dev_k4f(bid - 16, sC5, sC4, P + 4688, 4, 16, 1, 1, 1.f / 2048.f, g);
    }
}

// ---------------------------------------------------------------------------
__global__ __launch_bounds__(1024)
void kreduce(const float* __restrict__ P, int n, float* __restrict__ out)
{
    float s = 0.f;
    for (int i = threadIdx.x; i < n; i += 1024) s += P[i];
    float t = block_sum1024(s);
    if (threadIdx.x == 0) out[0] = t;
}

// ---------------------------------------------------------------------------
extern "C" void kernel_launch(void* const* d_in, const int* in_sizes, int n_in,
                              void* d_out, int out_size, void* d_ws, size_t ws_size,
                              hipStream_t stream)
{
    const float* in = (const float*)d_in[0];
    const float* tg = (const float*)d_in[1];
    float* out = (float*)d_out;

    GW g;
    {
        double u[9], S = 0.0;
        for (int k = 0; k < 9; ++k) { double d = k - 4; u[k] = exp(-0.5 * d * d); S += u[k]; }
        for (int k = 0; k < 9; ++k) g.w[k] = (float)(u[k] / S);
        g.A = (float)((2.0*u[0] + u[1] + u[3] + u[4]) / S);  // batch(2) reflect self-weight
        g.B = (float)((u[1] + 2.0*u[2] + u[3]) / S);         // cross-weight
    }

    // workspace layout (floats)
    float* T1  = (float*)d_ws;             // 2*64*128*128 = 2097152
    float* C1  = T1  + 2097152;            // 2*32*128*128 = 1048576
    float* C2  = C1  + 1048576;            // 2*16*64*64   = 131072
    float* C3  = C2  + 131072;             // 2*8*32*32    = 16384
    float* Tl1 = C3  + 16384;              // 2*32*64*64   = 262144
    float* Tl2 = Tl1 + 262144;             // 2*16*32*32   = 32768
    float* Tl3 = Tl2 + 32768;              // 2*8*16*16    = 4096
    float* V0  = Tl3 + 4096;               // 2*64*128*128 = 2097152
    float* P   = V0  + 2097152;            // 4696 partials (cap 8192)
    float* wend = P + 8192;
    __hip_bfloat16* DIFF = (__hip_bfloat16*)wend;
    const size_t base_bytes = (size_t)((char*)wend - (char*)d_ws);
    const size_t diff_bytes = (size_t)2 * 64 * 256 * 256 * sizeof(__hip_bfloat16);
    const int use_diff = (ws_size >= base_bytes + diff_bytes) ? 1 : 0;

    dim3 blk(256);

    // D1: level-0 WH-down of diff (+ bf16 DIFF x<132, + x>=132 partials)
    if (use_diff) k1l0<true ><<<dim3(2,8,128), blk, 0, stream>>>(in, tg, T1, DIFF, P, g);
    else          k1l0<false><<<dim3(2,8,128), blk, 0, stream>>>(in, tg, T1, nullptr, P, g);

    // D2: k2s0: T1 -> C1  (D=64, Dd=32, M4=4096)
    k2s<<<dim3(512), blk, 0, stream>>>(T1, C1, 64, 32, 4096, g);

    // D3: k1s1 (C1->Tl1, 256) || k3_0 (C1->V0, 1024)
    kD3<<<dim3(1280), blk, 0, stream>>>(C1, Tl1, V0, g);

    // D4: k2s1 (Tl1->C2, 64) || k4-L0 (3072)
    kD4<<<dim3(3136), blk, 0, stream>>>(Tl1, C2, V0, use_diff ? DIFF : nullptr,
                                        in, tg, use_diff, P, g);

    // D5: k1s2 (C2->Tl2, 64) || k4-L1 (512)
    kD5<<<dim3(576), blk, 0, stream>>>(C2, Tl2, C1, P, g);

    // D6: k2s2: Tl2 -> C3  (D=16, Dd=8, M4=256)
    k2s<<<dim3(8), blk, 0, stream>>>(Tl2, C3, 16, 8, 256, g);

    // D7: k1s3 (C3->Tl3, 16) || k4-L2 (64)
    kD7<<<dim3(80), blk, 0, stream>>>(C3, Tl3, C2, P, g);

    // D8: tailpar (L3: 16 blocks, L4: 8 blocks)
    tailpar<<<dim3(24), blk, 0, stream>>>(Tl3, C3, P, g);

    // D9: final reduce over 4696 partials
    kreduce<<<dim3(1), dim3(1024), 0, stream>>>(P, 4696, out);
}